// Round 1
// baseline (1044.411 us; speedup 1.0000x reference)
//
#include <hip/hip_runtime.h>

#define MTOK   32768   // B*L
#define LSEQ   4096
#define BSZ    8
#define DM     512
#define DC     256
#define DMAMBA 256
#define DST    64
#define NPROJ  1152    // 512 uv | 256 x_ssm | 256 dt | 64 B | 64 C
#define FFN_D  2048
#define NCH    64      // scan chunks per sequence
#define CLEN   64      // 4096/64

typedef __attribute__((ext_vector_type(4))) float          f32x4;
typedef __attribute__((ext_vector_type(8))) unsigned short u16x8;
typedef __attribute__((ext_vector_type(8))) __bf16         bf16x8;

static __device__ __forceinline__ unsigned short f2bf(float f) {
    unsigned int u = __builtin_bit_cast(unsigned int, f);
    u += 0x7fffu + ((u >> 16) & 1u);   // RNE
    return (unsigned short)(u >> 16);
}

static __device__ __forceinline__ float wred(float s) {
#pragma unroll
    for (int m = 1; m < 64; m <<= 1) s += __shfl_xor(s, m);
    return s;
}

static __device__ __forceinline__ f32x4 mfma16(u16x8 a, u16x8 b, f32x4 c) {
    return __builtin_amdgcn_mfma_f32_16x16x32_bf16(
        __builtin_bit_cast(bf16x8, a), __builtin_bit_cast(bf16x8, b), c, 0, 0, 0);
}

// ---------------------------------------------------------------------------
// Generic NT GEMM: C[M][N] = A[M][K] * Bt[N][K]^T, bf16 in, f32 acc.
// 128x128 tile, BK=32, 4 waves (2x2), each wave 64x64 via 4x4 16x16 frags.
// EPI 0: f32 out. 1: bf16 out. 2: dual-B, out = bf16(silu(AB1)*AB2).
// EPI 3: f32 out = Cin + AB  (residual add).
// ---------------------------------------------------------------------------
template <int EPI>
__global__ __launch_bounds__(256) void gemm_nt(
    const unsigned short* __restrict__ A, const unsigned short* __restrict__ Bt,
    const unsigned short* __restrict__ B2t, void* __restrict__ Cp,
    const float* __restrict__ Cin, int K, int ldc)
{
    __shared__ unsigned short As[128][40];   // +8 pad: row stride 80B -> <=2-way banks
    __shared__ unsigned short Bs[128][40];
    __shared__ unsigned short Bs2[128][40];

    const int tid = threadIdx.x;
    const int lane = tid & 63, wid = tid >> 6;
    const int wr = wid >> 1, wc = wid & 1;
    const long m0 = (long)blockIdx.x * 128;
    const long n0 = (long)blockIdx.y * 128;

    f32x4 acc[4][4], acc2[4][4];
#pragma unroll
    for (int i = 0; i < 4; i++)
#pragma unroll
        for (int j = 0; j < 4; j++) {
            acc[i][j] = f32x4{0.f, 0.f, 0.f, 0.f};
            acc2[i][j] = f32x4{0.f, 0.f, 0.f, 0.f};
        }

    const int srow = tid >> 1, scol = (tid & 1) * 16;
    const unsigned short* ag = A + (m0 + srow) * (long)K + scol;
    const unsigned short* bg = Bt + (n0 + srow) * (long)K + scol;
    const unsigned short* b2g = (EPI == 2) ? (B2t + (n0 + srow) * (long)K + scol) : nullptr;

    const int fr = lane & 15, fo = (lane >> 4) * 8;

    for (int k0 = 0; k0 < K; k0 += 32) {
        u16x8 a0 = *(const u16x8*)(ag + k0);
        u16x8 a1 = *(const u16x8*)(ag + k0 + 8);
        u16x8 b0 = *(const u16x8*)(bg + k0);
        u16x8 b1 = *(const u16x8*)(bg + k0 + 8);
        u16x8 c0, c1;
        if (EPI == 2) { c0 = *(const u16x8*)(b2g + k0); c1 = *(const u16x8*)(b2g + k0 + 8); }
        __syncthreads();   // protect prev-iter LDS reads
        *(u16x8*)&As[srow][scol]     = a0;
        *(u16x8*)&As[srow][scol + 8] = a1;
        *(u16x8*)&Bs[srow][scol]     = b0;
        *(u16x8*)&Bs[srow][scol + 8] = b1;
        if (EPI == 2) { *(u16x8*)&Bs2[srow][scol] = c0; *(u16x8*)&Bs2[srow][scol + 8] = c1; }
        __syncthreads();

        u16x8 av[4], bv[4], cv[4];
#pragma unroll
        for (int i = 0; i < 4; i++) av[i] = *(const u16x8*)&As[wr * 64 + i * 16 + fr][fo];
#pragma unroll
        for (int j = 0; j < 4; j++) bv[j] = *(const u16x8*)&Bs[wc * 64 + j * 16 + fr][fo];
        if (EPI == 2) {
#pragma unroll
            for (int j = 0; j < 4; j++) cv[j] = *(const u16x8*)&Bs2[wc * 64 + j * 16 + fr][fo];
        }
#pragma unroll
        for (int i = 0; i < 4; i++)
#pragma unroll
            for (int j = 0; j < 4; j++) {
                acc[i][j] = mfma16(av[i], bv[j], acc[i][j]);
                if (EPI == 2) acc2[i][j] = mfma16(av[i], cv[j], acc2[i][j]);
            }
    }

    // C/D layout (measured): col = lane&15, row = (lane>>4)*4 + reg
    const int frow = (lane >> 4) * 4;
#pragma unroll
    for (int i = 0; i < 4; i++)
#pragma unroll
        for (int j = 0; j < 4; j++)
#pragma unroll
            for (int r = 0; r < 4; r++) {
                long row = m0 + wr * 64 + i * 16 + frow + r;
                long col = n0 + wc * 64 + j * 16 + fr;
                long idx = row * (long)ldc + col;
                float v = acc[i][j][r];
                if (EPI == 0) {
                    ((float*)Cp)[idx] = v;
                } else if (EPI == 1) {
                    ((unsigned short*)Cp)[idx] = f2bf(v);
                } else if (EPI == 2) {
                    float h3 = acc2[i][j][r];
                    float s = v / (1.f + __expf(-v));
                    ((unsigned short*)Cp)[idx] = f2bf(s * h3);
                } else {
                    ((float*)Cp)[idx] = Cin[idx] + v;
                }
            }
}

// ---------------------------------------------------------------------------
// Weight transpose + bf16 cast: src[K][N] (f32) -> dst[N][K] (bf16)
// ---------------------------------------------------------------------------
__global__ void transpose_w_k(const float* __restrict__ src, unsigned short* __restrict__ dst,
                              int Kd, int Nd)
{
    int i = blockIdx.x * 256 + threadIdx.x;
    if (i < Kd * Nd) {
        int k = i / Nd, n = i % Nd;
        dst[(long)n * Kd + k] = f2bf(src[i]);
    }
}

// ---------------------------------------------------------------------------
// RMSNorm(x) * w -> bf16. One wave per token (512 elems, 8/lane).
// ---------------------------------------------------------------------------
__global__ __launch_bounds__(256) void rmsnorm1_k(const float* __restrict__ x,
                                                  const float* __restrict__ w,
                                                  unsigned short* __restrict__ out)
{
    const int lane = threadIdx.x & 63, wv = threadIdx.x >> 6;
    const long tok = (long)blockIdx.x * 4 + wv;
    const float* xr = x + tok * DM;
    float4 v[2];
    float s = 0.f;
#pragma unroll
    for (int j = 0; j < 2; j++) {
        int d0 = j * 256 + lane * 4;
        v[j] = *(const float4*)(xr + d0);
        s += v[j].x * v[j].x + v[j].y * v[j].y + v[j].z * v[j].z + v[j].w * v[j].w;
    }
    s = wred(s);
    float r = rsqrtf(s * (1.f / DM) + 1e-6f);
#pragma unroll
    for (int j = 0; j < 2; j++) {
        int d0 = j * 256 + lane * 4;
        const float4 ww = *(const float4*)(w + d0);
        *(ushort4*)(out + tok * DM + d0) = make_ushort4(
            f2bf(v[j].x * r * ww.x), f2bf(v[j].y * r * ww.y),
            f2bf(v[j].z * r * ww.z), f2bf(v[j].w * r * ww.w));
    }
}

// ---------------------------------------------------------------------------
// Per-token mamba prep. One wave per token.
// proj row layout: [0,512)=uv  [512,768)=x_ssm  [768,1024)=dt_raw  [1024,1088)=B  [1088,1152)=C
// Outputs: decay/inp f32 [M][256], cmn f32 [M][64], conv_out*silu(g) -> mixin[:, :256] bf16
// ---------------------------------------------------------------------------
__global__ __launch_bounds__(256) void mamba_prep_k(
    const float* __restrict__ proj, const float* __restrict__ dt_b,
    const float* __restrict__ A_log, const float* __restrict__ conv_w,
    const float* __restrict__ conv_b,
    float* __restrict__ decay, float* __restrict__ inp, float* __restrict__ cmn,
    unsigned short* __restrict__ mixin)
{
    const int lane = threadIdx.x & 63, wv = threadIdx.x >> 6;
    const long tok = (long)blockIdx.x * 4 + wv;
    const int l = (int)(tok & (LSEQ - 1));
    const float* pr = proj + tok * NPROJ;

    // B/C row norms over DSTATE=64 (one element per lane)
    float bv = pr[1024 + lane];
    float cv = pr[1088 + lane];
    float nb2 = wred(bv * bv);
    float nc2 = wred(cv * cv);
    float rb = 1.f / fmaxf(sqrtf(nb2), 1.f);
    float rc = 1.f / fmaxf(sqrtf(nc2), 1.f);
    float bn = bv * rb;
    cmn[tok * DST + lane] = cv * rc;

#pragma unroll
    for (int j = 0; j < 4; j++) {
        int d = j * 64 + lane;          // d%64 == lane  -> Bfull[d] = bn (this lane's)
        float dtr = pr[768 + d] + dt_b[d];
        dtr = fminf(fmaxf(dtr, -10.f), 5.f);
        float sp = log1pf(__expf(dtr));
        float dt = fminf(fmaxf(sp, 1e-4f), 0.1f);
        float a = -__expf(A_log[d]);
        decay[tok * DMAMBA + d] = __expf(dt * a);
        inp[tok * DMAMBA + d] = dt * bn * pr[512 + d];

        // depthwise causal conv, K=3 (channel d)
        float ul  = pr[d];
        float um1 = (l >= 1) ? pr[d - NPROJ] : 0.f;
        float um2 = (l >= 2) ? pr[d - 2 * NPROJ] : 0.f;
        float conv = conv_b[d] + um2 * conv_w[d * 3] + um1 * conv_w[d * 3 + 1] + ul * conv_w[d * 3 + 2];
        float g = pr[256 + d];
        float sg = g / (1.f + __expf(-g));
        mixin[tok * DM + d] = f2bf(conv * sg);
    }
}

// ---------------------------------------------------------------------------
// Chunked scan h[l] = decay[l]*h[l-1] + inp[l].  Phase A: per-chunk (P, S).
// ---------------------------------------------------------------------------
__global__ __launch_bounds__(256) void scan_chunk_k(const float* __restrict__ decay,
                                                    const float* __restrict__ inp,
                                                    float* __restrict__ P, float* __restrict__ S)
{
    const int bc = blockIdx.x;            // b*NCH + c
    const int b = bc >> 6, c = bc & 63;
    const int d = threadIdx.x;
    long base = ((long)b * LSEQ + (long)c * CLEN) * DMAMBA + d;
    float h = 0.f, p = 1.f;
    for (int t = 0; t < CLEN; t++) {
        float dec = decay[base + (long)t * DMAMBA];
        float iv = inp[base + (long)t * DMAMBA];
        h = dec * h + iv;
        p *= dec;
    }
    P[(long)bc * DMAMBA + d] = p;
    S[(long)bc * DMAMBA + d] = h;
}

// Phase B: sequential prefix over chunks per (b,d); carry[c] = h entering chunk c.
__global__ __launch_bounds__(256) void scan_prefix_k(const float* __restrict__ P,
                                                     const float* __restrict__ S,
                                                     float* __restrict__ carry)
{
    const int b = blockIdx.x, d = threadIdx.x;
    float H = 0.f;
    for (int c = 0; c < NCH; c++) {
        long i = ((long)b * NCH + c) * DMAMBA + d;
        carry[i] = H;
        H = P[i] * H + S[i];
    }
}

// Phase C: replay chunk with carry, fuse y = h*Cfull + D*x_ssm -> bf16.
__global__ __launch_bounds__(256) void scan_finish_k(
    const float* __restrict__ decay, const float* __restrict__ inp,
    const float* __restrict__ carry, const float* __restrict__ cmn,
    const float* __restrict__ Dw, const float* __restrict__ proj,
    unsigned short* __restrict__ y)
{
    const int bc = blockIdx.x;
    const int b = bc >> 6, c = bc & 63;
    const int d = threadIdx.x;
    const long tok0 = (long)b * LSEQ + (long)c * CLEN;
    float h = carry[(long)bc * DMAMBA + d];
    const float dv = Dw[d];
    for (int t = 0; t < CLEN; t++) {
        long tok = tok0 + t;
        long idx = tok * DMAMBA + d;
        h = decay[idx] * h + inp[idx];
        float yv = h * cmn[tok * DST + (d & 63)] + dv * proj[tok * NPROJ + 512 + d];
        y[idx] = f2bf(yv);
    }
}

// ---------------------------------------------------------------------------
// velocity/x update + RMSNorm -> normed bf16. One wave per token.
// outV = beta*vel + mixer ; outX = x + outV ; normed = rms(outX)*ffn_w
// ---------------------------------------------------------------------------
__global__ __launch_bounds__(256) void update_norm_k(
    const float* __restrict__ x, const float* __restrict__ vel,
    const float* __restrict__ mixer, const float* __restrict__ lbeta,
    const float* __restrict__ fw, float* __restrict__ outX,
    float* __restrict__ outV, unsigned short* __restrict__ normed)
{
    const int lane = threadIdx.x & 63, wv = threadIdx.x >> 6;
    const long tok = (long)blockIdx.x * 4 + wv;
    const float beta = 1.f / (1.f + __expf(-lbeta[0]));
    float xs[8];
    float s = 0.f;
#pragma unroll
    for (int j = 0; j < 2; j++) {
        const int d0 = j * 256 + lane * 4;
        const float4 xv = *(const float4*)(x + tok * DM + d0);
        const float4 vv = *(const float4*)(vel + tok * DM + d0);
        const float4 mv = *(const float4*)(mixer + tok * DM + d0);
        float4 vn, xn;
        vn.x = beta * vv.x + mv.x; xn.x = xv.x + vn.x;
        vn.y = beta * vv.y + mv.y; xn.y = xv.y + vn.y;
        vn.z = beta * vv.z + mv.z; xn.z = xv.z + vn.z;
        vn.w = beta * vv.w + mv.w; xn.w = xv.w + vn.w;
        *(float4*)(outV + tok * DM + d0) = vn;
        *(float4*)(outX + tok * DM + d0) = xn;
        s += xn.x * xn.x + xn.y * xn.y + xn.z * xn.z + xn.w * xn.w;
        xs[j * 4 + 0] = xn.x; xs[j * 4 + 1] = xn.y; xs[j * 4 + 2] = xn.z; xs[j * 4 + 3] = xn.w;
    }
    s = wred(s);
    const float r = rsqrtf(s * (1.f / DM) + 1e-6f);
#pragma unroll
    for (int j = 0; j < 2; j++) {
        const int d0 = j * 256 + lane * 4;
        const float4 ww = *(const float4*)(fw + d0);
        *(ushort4*)(normed + tok * DM + d0) = make_ushort4(
            f2bf(xs[j * 4 + 0] * r * ww.x), f2bf(xs[j * 4 + 1] * r * ww.y),
            f2bf(xs[j * 4 + 2] * r * ww.z), f2bf(xs[j * 4 + 3] * r * ww.w));
    }
}

// ---------------------------------------------------------------------------
extern "C" void kernel_launch(void* const* d_in, const int* in_sizes, int n_in,
                              void* d_out, int out_size, void* d_ws, size_t ws_size,
                              hipStream_t stream)
{
    (void)in_sizes; (void)n_in; (void)out_size; (void)ws_size;

    const float* x          = (const float*)d_in[0];
    const float* velocity   = (const float*)d_in[1];
    const float* pre_norm_w = (const float*)d_in[2];
    const float* conv_in_w  = (const float*)d_in[3];
    const float* conv_dw_w  = (const float*)d_in[4];
    const float* conv_dw_b  = (const float*)d_in[5];
    const float* x_proj_w   = (const float*)d_in[6];
    const float* dt_w       = (const float*)d_in[7];
    const float* dt_b       = (const float*)d_in[8];
    const float* B_w        = (const float*)d_in[9];
    const float* C_w        = (const float*)d_in[10];
    const float* A_log      = (const float*)d_in[11];
    const float* Dw         = (const float*)d_in[12];
    const float* ssm_out_w  = (const float*)d_in[13];
    const float* out_proj_w = (const float*)d_in[14];
    const float* log_beta   = (const float*)d_in[15];
    const float* ffn_norm_w = (const float*)d_in[16];
    const float* w1         = (const float*)d_in[17];
    const float* w3         = (const float*)d_in[18];
    const float* w2         = (const float*)d_in[19];

    char* base = (char*)d_ws;
    size_t off = 0;
    auto take = [&](size_t bytes) -> void* {
        void* p = base + off;
        off = (off + bytes + 255) & ~(size_t)255;
        return p;
    };
    unsigned short* WCAT  = (unsigned short*)take((size_t)NPROJ * DM * 2);
    unsigned short* SSMT  = (unsigned short*)take((size_t)DMAMBA * DMAMBA * 2);
    unsigned short* OUTPT = (unsigned short*)take((size_t)DM * DM * 2);
    unsigned short* W1T   = (unsigned short*)take((size_t)FFN_D * DM * 2);
    unsigned short* W3T   = (unsigned short*)take((size_t)FFN_D * DM * 2);
    unsigned short* W2T   = (unsigned short*)take((size_t)DM * FFN_D * 2);
    unsigned short* XN    = (unsigned short*)take((size_t)MTOK * DM * 2);
    float* PROJ  = (float*)take((size_t)MTOK * NPROJ * 4);
    float* DECAY = (float*)take((size_t)MTOK * DMAMBA * 4);
    float* INP   = (float*)take((size_t)MTOK * DMAMBA * 4);
    float* CMN   = (float*)take((size_t)MTOK * DST * 4);
    float* PP    = (float*)take((size_t)BSZ * NCH * DMAMBA * 4);
    float* SS    = (float*)take((size_t)BSZ * NCH * DMAMBA * 4);
    float* CARRY = (float*)take((size_t)BSZ * NCH * DMAMBA * 4);
    unsigned short* Y      = (unsigned short*)take((size_t)MTOK * DMAMBA * 2);
    unsigned short* MIXIN  = (unsigned short*)take((size_t)MTOK * DM * 2);
    unsigned short* NORMED = (unsigned short*)take((size_t)MTOK * DM * 2);
    // Overlays (lifetimes disjoint): MIXER over DECAY+INP (dead after scan),
    // ACT over XN+PROJ (dead after scan_finish / proj gemm).
    float* MIXER = DECAY;
    unsigned short* ACT = XN;
    float* outX = (float*)d_out;
    float* outV = outX + (size_t)MTOK * DM;

    // --- weight prep: f32 [K][N] -> bf16 [N][K] ---
    auto T = [&](const float* s, unsigned short* dst, int K, int N) {
        int n = K * N;
        transpose_w_k<<<(n + 255) / 256, 256, 0, stream>>>(s, dst, K, N);
    };
    T(conv_in_w, WCAT, DM, DM);
    T(x_proj_w, WCAT + 512 * DM, DM, DMAMBA);
    T(dt_w, WCAT + 768 * DM, DM, DMAMBA);
    T(B_w, WCAT + 1024 * DM, DM, DST);
    T(C_w, WCAT + 1088 * DM, DM, DST);
    T(ssm_out_w, SSMT, DMAMBA, DMAMBA);
    T(out_proj_w, OUTPT, DM, DM);
    T(w1, W1T, DM, FFN_D);
    T(w3, W3T, DM, FFN_D);
    T(w2, W2T, FFN_D, DM);

    // --- pipeline ---
    rmsnorm1_k<<<MTOK / 4, 256, 0, stream>>>(x, pre_norm_w, XN);

    gemm_nt<0><<<dim3(MTOK / 128, NPROJ / 128), 256, 0, stream>>>(
        XN, WCAT, nullptr, PROJ, nullptr, DM, NPROJ);

    mamba_prep_k<<<MTOK / 4, 256, 0, stream>>>(PROJ, dt_b, A_log, conv_dw_w, conv_dw_b,
                                               DECAY, INP, CMN, MIXIN);

    scan_chunk_k<<<BSZ * NCH, 256, 0, stream>>>(DECAY, INP, PP, SS);
    scan_prefix_k<<<BSZ, 256, 0, stream>>>(PP, SS, CARRY);
    scan_finish_k<<<BSZ * NCH, 256, 0, stream>>>(DECAY, INP, CARRY, CMN, Dw, PROJ, Y);

    // ssm_out GEMM writes bf16 directly into mixin[:, 256:512]
    gemm_nt<1><<<dim3(MTOK / 128, DMAMBA / 128), 256, 0, stream>>>(
        Y, SSMT, nullptr, (void*)(MIXIN + 256), nullptr, DMAMBA, DM);

    gemm_nt<0><<<dim3(MTOK / 128, DM / 128), 256, 0, stream>>>(
        MIXIN, OUTPT, nullptr, MIXER, nullptr, DM, DM);

    update_norm_k<<<MTOK / 4, 256, 0, stream>>>(x, velocity, MIXER, log_beta, ffn_norm_w,
                                                outX, outV, NORMED);

    // FFN: act = bf16(silu(normed@w1) * (normed@w3))
    gemm_nt<2><<<dim3(MTOK / 128, FFN_D / 128), 256, 0, stream>>>(
        NORMED, W1T, W3T, ACT, nullptr, DM, FFN_D);

    // x_out = x_new + act@w2   (x_new already in d_out first half)
    gemm_nt<3><<<dim3(MTOK / 128, DM / 128), 256, 0, stream>>>(
        ACT, W2T, nullptr, (void*)outX, (const float*)outX, FFN_D, DM);
}

// Round 3
// 1001.781 us; speedup vs baseline: 1.0426x; 1.0426x over previous
//
#include <hip/hip_runtime.h>

#define MTOK   32768   // B*L
#define LSEQ   4096
#define BSZ    8
#define DM     512
#define DC     256
#define DMAMBA 256
#define DST    64
#define NPROJ  1152    // 512 uv | 256 x_ssm | 256 dt | 64 B | 64 C
#define FFN_D  2048
#define NCH    64      // scan chunks per sequence
#define CLEN   64      // 4096/64

typedef __attribute__((ext_vector_type(4))) float          f32x4;
typedef __attribute__((ext_vector_type(8))) unsigned short u16x8;
typedef __attribute__((ext_vector_type(8))) __bf16         bf16x8;

typedef const __attribute__((address_space(1))) unsigned int* gptr_t;
typedef __attribute__((address_space(3))) unsigned int*       lptr_t;

static __device__ __forceinline__ unsigned short f2bf(float f) {
    unsigned int u = __builtin_bit_cast(unsigned int, f);
    u += 0x7fffu + ((u >> 16) & 1u);   // RNE
    return (unsigned short)(u >> 16);
}

static __device__ __forceinline__ float wred(float s) {
#pragma unroll
    for (int m = 1; m < 64; m <<= 1) s += __shfl_xor(s, m);
    return s;
}

static __device__ __forceinline__ f32x4 mfma16(u16x8 a, u16x8 b, f32x4 c) {
    return __builtin_amdgcn_mfma_f32_16x16x32_bf16(
        __builtin_bit_cast(bf16x8, a), __builtin_bit_cast(bf16x8, b), c, 0, 0, 0);
}

// async global->LDS, 16B per lane, dest = wave-uniform base + lane*16
static __device__ __forceinline__ void gl16(const unsigned short* g, unsigned short* l) {
    __builtin_amdgcn_global_load_lds((gptr_t)g, (lptr_t)l, 16, 0, 0);
}

// ---------------------------------------------------------------------------
// NT GEMM (m97 structure): C[M][N] = A[M][K] * Bt[N][K]^T, bf16 in, f32 acc.
// 128x128 tile, BK=32, 4 waves (2x2), linear LDS [128][32], global_load_lds.
// Grid: (N/128, M/128)  -- blockIdx.x over N so consecutive blocks share A-tile.
// EPI 0: f32 out. 1: bf16 out. 2: dual-B, out = bf16(silu(AB1)*AB2).
// EPI 3: f32 out = Cin + AB  (residual add).
// ---------------------------------------------------------------------------
template <int EPI>
__global__ __launch_bounds__(256) void gemm_nt(
    const unsigned short* __restrict__ A, const unsigned short* __restrict__ Bt,
    const unsigned short* __restrict__ B2t, void* __restrict__ Cp,
    const float* __restrict__ Cin, int K, int ldc)
{
    __shared__ unsigned short As[128 * 32];
    __shared__ unsigned short Bs[128 * 32];
    __shared__ unsigned short Bs2[(EPI == 2) ? 128 * 32 : 8];

    const int tid = threadIdx.x;
    const int lane = tid & 63, wid = tid >> 6;
    const int wr = wid >> 1, wc = wid & 1;
    const long n0 = (long)blockIdx.x * 128;
    const long m0 = (long)blockIdx.y * 128;

    f32x4 acc[4][4], acc2[4][4];
#pragma unroll
    for (int i = 0; i < 4; i++)
#pragma unroll
        for (int j = 0; j < 4; j++) {
            acc[i][j] = f32x4{0.f, 0.f, 0.f, 0.f};
            acc2[i][j] = f32x4{0.f, 0.f, 0.f, 0.f};
        }

    // staging map: wave w covers LDS rows [w*32, w*32+32); inst q covers 16 rows.
    // lane l -> row = w*32 + q*16 + l/4, col = (l&3)*8  (16B per lane)
    const int srow = wid * 32 + (lane >> 2);
    const int scol = (lane & 3) * 8;
    const unsigned short* agp = A + (m0 + srow) * (long)K + scol;
    const unsigned short* bgp = Bt + (n0 + srow) * (long)K + scol;
    const unsigned short* b2gp = (EPI == 2) ? (B2t + (n0 + srow) * (long)K + scol) : nullptr;
    unsigned short* lA = As + wid * 1024;
    unsigned short* lB = Bs + wid * 1024;
    unsigned short* lB2 = (EPI == 2) ? (Bs2 + wid * 1024) : nullptr;

    const int fr = lane & 15, fo = (lane >> 4) * 8;
    const long skip = 16 * (long)K;

    for (int k0 = 0; k0 < K; k0 += 32) {
        gl16(agp + k0, lA);
        gl16(agp + k0 + skip, lA + 512);
        gl16(bgp + k0, lB);
        gl16(bgp + k0 + skip, lB + 512);
        if constexpr (EPI == 2) {
            gl16(b2gp + k0, lB2);
            gl16(b2gp + k0 + skip, lB2 + 512);
        }
        __syncthreads();   // drains vmcnt -> staged tile visible to all waves

        u16x8 av[4], bv[4], cv[4];
#pragma unroll
        for (int i = 0; i < 4; i++)
            av[i] = *(const u16x8*)(As + (wr * 64 + i * 16 + fr) * 32 + fo);
#pragma unroll
        for (int j = 0; j < 4; j++)
            bv[j] = *(const u16x8*)(Bs + (wc * 64 + j * 16 + fr) * 32 + fo);
        if constexpr (EPI == 2) {
#pragma unroll
            for (int j = 0; j < 4; j++)
                cv[j] = *(const u16x8*)(Bs2 + (wc * 64 + j * 16 + fr) * 32 + fo);
        }
#pragma unroll
        for (int i = 0; i < 4; i++)
#pragma unroll
            for (int j = 0; j < 4; j++) {
                acc[i][j] = mfma16(av[i], bv[j], acc[i][j]);
                if constexpr (EPI == 2) acc2[i][j] = mfma16(av[i], cv[j], acc2[i][j]);
            }
        __syncthreads();   // all reads done before next-iter overwrite
    }

    // C/D layout (verified): col = lane&15, row = (lane>>4)*4 + reg
    const int frow = (lane >> 4) * 4;
#pragma unroll
    for (int i = 0; i < 4; i++)
#pragma unroll
        for (int j = 0; j < 4; j++)
#pragma unroll
            for (int r = 0; r < 4; r++) {
                long row = m0 + wr * 64 + i * 16 + frow + r;
                long col = n0 + wc * 64 + j * 16 + fr;
                long idx = row * (long)ldc + col;
                float v = acc[i][j][r];
                if constexpr (EPI == 0) {
                    ((float*)Cp)[idx] = v;
                } else if constexpr (EPI == 1) {
                    ((unsigned short*)Cp)[idx] = f2bf(v);
                } else if constexpr (EPI == 2) {
                    float h3 = acc2[i][j][r];
                    float s = v / (1.f + __expf(-v));
                    ((unsigned short*)Cp)[idx] = f2bf(s * h3);
                } else {
                    ((float*)Cp)[idx] = Cin[idx] + v;
                }
            }
}

// ---------------------------------------------------------------------------
// All weight transposes fused: src[K][N] (f32) -> dst[N][K] (bf16), 10 tables
// ---------------------------------------------------------------------------
struct TD { const float* s; unsigned short* d; int K, N, nb; };
struct TP { TD t[10]; };

__global__ __launch_bounds__(256) void transpose_all_k(TP p)
{
    int b = blockIdx.x;
#pragma unroll
    for (int i = 0; i < 10; i++) {
        TD td = p.t[i];
        if (b < td.nb) {
            int idx = b * 256 + threadIdx.x;
            if (idx < td.K * td.N) {
                int k = idx / td.N, n = idx - k * td.N;
                td.d[(long)n * td.K + k] = f2bf(td.s[idx]);
            }
            return;
        }
        b -= td.nb;
    }
}

// ---------------------------------------------------------------------------
// RMSNorm(x) * w -> bf16. One wave per token (512 elems, 8/lane).
// ---------------------------------------------------------------------------
__global__ __launch_bounds__(256) void rmsnorm1_k(const float* __restrict__ x,
                                                  const float* __restrict__ w,
                                                  unsigned short* __restrict__ out)
{
    const int lane = threadIdx.x & 63, wv = threadIdx.x >> 6;
    const long tok = (long)blockIdx.x * 4 + wv;
    const float* xr = x + tok * DM;
    float4 v[2];
    float s = 0.f;
#pragma unroll
    for (int j = 0; j < 2; j++) {
        int d0 = j * 256 + lane * 4;
        v[j] = *(const float4*)(xr + d0);
        s += v[j].x * v[j].x + v[j].y * v[j].y + v[j].z * v[j].z + v[j].w * v[j].w;
    }
    s = wred(s);
    float r = rsqrtf(s * (1.f / DM) + 1e-6f);
#pragma unroll
    for (int j = 0; j < 2; j++) {
        int d0 = j * 256 + lane * 4;
        const float4 ww = *(const float4*)(w + d0);
        *(ushort4*)(out + tok * DM + d0) = make_ushort4(
            f2bf(v[j].x * r * ww.x), f2bf(v[j].y * r * ww.y),
            f2bf(v[j].z * r * ww.z), f2bf(v[j].w * r * ww.w));
    }
}

// ---------------------------------------------------------------------------
// Per-token mamba prep. One wave per token.
// proj row: [0,512)=uv  [512,768)=x_ssm  [768,1024)=dt_raw  [1024,1088)=B  [1088,1152)=C
// ---------------------------------------------------------------------------
__global__ __launch_bounds__(256) void mamba_prep_k(
    const float* __restrict__ proj, const float* __restrict__ dt_b,
    const float* __restrict__ A_log, const float* __restrict__ conv_w,
    const float* __restrict__ conv_b,
    float* __restrict__ decay, float* __restrict__ inp, float* __restrict__ cmn,
    unsigned short* __restrict__ mixin)
{
    const int lane = threadIdx.x & 63, wv = threadIdx.x >> 6;
    const long tok = (long)blockIdx.x * 4 + wv;
    const int l = (int)(tok & (LSEQ - 1));
    const float* pr = proj + tok * NPROJ;

    float bv = pr[1024 + lane];
    float cv = pr[1088 + lane];
    float nb2 = wred(bv * bv);
    float nc2 = wred(cv * cv);
    float rb = 1.f / fmaxf(sqrtf(nb2), 1.f);
    float rc = 1.f / fmaxf(sqrtf(nc2), 1.f);
    float bn = bv * rb;
    cmn[tok * DST + lane] = cv * rc;

#pragma unroll
    for (int j = 0; j < 4; j++) {
        int d = j * 64 + lane;          // d%64 == lane  -> Bfull[d] = bn
        float dtr = pr[768 + d] + dt_b[d];
        dtr = fminf(fmaxf(dtr, -10.f), 5.f);
        float sp = log1pf(__expf(dtr));
        float dt = fminf(fmaxf(sp, 1e-4f), 0.1f);
        float a = -__expf(A_log[d]);
        decay[tok * DMAMBA + d] = __expf(dt * a);
        inp[tok * DMAMBA + d] = dt * bn * pr[512 + d];

        float ul  = pr[d];
        float um1 = (l >= 1) ? pr[d - NPROJ] : 0.f;
        float um2 = (l >= 2) ? pr[d - 2 * NPROJ] : 0.f;
        float conv = conv_b[d] + um2 * conv_w[d * 3] + um1 * conv_w[d * 3 + 1] + ul * conv_w[d * 3 + 2];
        float g = pr[256 + d];
        float sg = g / (1.f + __expf(-g));
        mixin[tok * DM + d] = f2bf(conv * sg);
    }
}

// ---------------------------------------------------------------------------
// Chunked scan h[l] = decay[l]*h[l-1] + inp[l].
// ---------------------------------------------------------------------------
__global__ __launch_bounds__(256) void scan_chunk_k(const float* __restrict__ decay,
                                                    const float* __restrict__ inp,
                                                    float* __restrict__ P, float* __restrict__ S)
{
    const int bc = blockIdx.x;
    const int b = bc >> 6, c = bc & 63;
    const int d = threadIdx.x;
    long base = ((long)b * LSEQ + (long)c * CLEN) * DMAMBA + d;
    float h = 0.f, p = 1.f;
    for (int t = 0; t < CLEN; t++) {
        float dec = decay[base + (long)t * DMAMBA];
        float iv = inp[base + (long)t * DMAMBA];
        h = dec * h + iv;
        p *= dec;
    }
    P[(long)bc * DMAMBA + d] = p;
    S[(long)bc * DMAMBA + d] = h;
}

__global__ __launch_bounds__(256) void scan_prefix_k(const float* __restrict__ P,
                                                     const float* __restrict__ S,
                                                     float* __restrict__ carry)
{
    const int b = blockIdx.x, d = threadIdx.x;
    float H = 0.f;
    for (int c = 0; c < NCH; c++) {
        long i = ((long)b * NCH + c) * DMAMBA + d;
        carry[i] = H;
        H = P[i] * H + S[i];
    }
}

__global__ __launch_bounds__(256) void scan_finish_k(
    const float* __restrict__ decay, const float* __restrict__ inp,
    const float* __restrict__ carry, const float* __restrict__ cmn,
    const float* __restrict__ Dw, const float* __restrict__ proj,
    unsigned short* __restrict__ y)
{
    const int bc = blockIdx.x;
    const int b = bc >> 6, c = bc & 63;
    const int d = threadIdx.x;
    const long tok0 = (long)b * LSEQ + (long)c * CLEN;
    float h = carry[(long)bc * DMAMBA + d];
    const float dv = Dw[d];
    for (int t = 0; t < CLEN; t++) {
        long tok = tok0 + t;
        long idx = tok * DMAMBA + d;
        h = decay[idx] * h + inp[idx];
        float yv = h * cmn[tok * DST + (d & 63)] + dv * proj[tok * NPROJ + 512 + d];
        y[idx] = f2bf(yv);
    }
}

// ---------------------------------------------------------------------------
// velocity/x update + RMSNorm -> normed bf16. One wave per token.
// ---------------------------------------------------------------------------
__global__ __launch_bounds__(256) void update_norm_k(
    const float* __restrict__ x, const float* __restrict__ vel,
    const float* __restrict__ mixer, const float* __restrict__ lbeta,
    const float* __restrict__ fw, float* __restrict__ outX,
    float* __restrict__ outV, unsigned short* __restrict__ normed)
{
    const int lane = threadIdx.x & 63, wv = threadIdx.x >> 6;
    const long tok = (long)blockIdx.x * 4 + wv;
    const float beta = 1.f / (1.f + __expf(-lbeta[0]));
    float xs[8];
    float s = 0.f;
#pragma unroll
    for (int j = 0; j < 2; j++) {
        const int d0 = j * 256 + lane * 4;
        const float4 xv = *(const float4*)(x + tok * DM + d0);
        const float4 vv = *(const float4*)(vel + tok * DM + d0);
        const float4 mv = *(const float4*)(mixer + tok * DM + d0);
        float4 vn, xn;
        vn.x = beta * vv.x + mv.x; xn.x = xv.x + vn.x;
        vn.y = beta * vv.y + mv.y; xn.y = xv.y + vn.y;
        vn.z = beta * vv.z + mv.z; xn.z = xv.z + vn.z;
        vn.w = beta * vv.w + mv.w; xn.w = xv.w + vn.w;
        *(float4*)(outV + tok * DM + d0) = vn;
        *(float4*)(outX + tok * DM + d0) = xn;
        s += xn.x * xn.x + xn.y * xn.y + xn.z * xn.z + xn.w * xn.w;
        xs[j * 4 + 0] = xn.x; xs[j * 4 + 1] = xn.y; xs[j * 4 + 2] = xn.z; xs[j * 4 + 3] = xn.w;
    }
    s = wred(s);
    const float r = rsqrtf(s * (1.f / DM) + 1e-6f);
#pragma unroll
    for (int j = 0; j < 2; j++) {
        const int d0 = j * 256 + lane * 4;
        const float4 ww = *(const float4*)(fw + d0);
        *(ushort4*)(normed + tok * DM + d0) = make_ushort4(
            f2bf(xs[j * 4 + 0] * r * ww.x), f2bf(xs[j * 4 + 1] * r * ww.y),
            f2bf(xs[j * 4 + 2] * r * ww.z), f2bf(xs[j * 4 + 3] * r * ww.w));
    }
}

// ---------------------------------------------------------------------------
extern "C" void kernel_launch(void* const* d_in, const int* in_sizes, int n_in,
                              void* d_out, int out_size, void* d_ws, size_t ws_size,
                              hipStream_t stream)
{
    (void)in_sizes; (void)n_in; (void)out_size; (void)ws_size;

    const float* x          = (const float*)d_in[0];
    const float* velocity   = (const float*)d_in[1];
    const float* pre_norm_w = (const float*)d_in[2];
    const float* conv_in_w  = (const float*)d_in[3];
    const float* conv_dw_w  = (const float*)d_in[4];
    const float* conv_dw_b  = (const float*)d_in[5];
    const float* x_proj_w   = (const float*)d_in[6];
    const float* dt_w       = (const float*)d_in[7];
    const float* dt_b       = (const float*)d_in[8];
    const float* B_w        = (const float*)d_in[9];
    const float* C_w        = (const float*)d_in[10];
    const float* A_log      = (const float*)d_in[11];
    const float* Dw         = (const float*)d_in[12];
    const float* ssm_out_w  = (const float*)d_in[13];
    const float* out_proj_w = (const float*)d_in[14];
    const float* log_beta   = (const float*)d_in[15];
    const float* ffn_norm_w = (const float*)d_in[16];
    const float* w1         = (const float*)d_in[17];
    const float* w3         = (const float*)d_in[18];
    const float* w2         = (const float*)d_in[19];

    char* base = (char*)d_ws;
    size_t off = 0;
    auto take = [&](size_t bytes) -> void* {
        void* p = base + off;
        off = (off + bytes + 255) & ~(size_t)255;
        return p;
    };
    unsigned short* WCAT  = (unsigned short*)take((size_t)NPROJ * DM * 2);
    unsigned short* SSMT  = (unsigned short*)take((size_t)DMAMBA * DMAMBA * 2);
    unsigned short* OUTPT = (unsigned short*)take((size_t)DM * DM * 2);
    unsigned short* W1T   = (unsigned short*)take((size_t)FFN_D * DM * 2);
    unsigned short* W3T   = (unsigned short*)take((size_t)FFN_D * DM * 2);
    unsigned short* W2T   = (unsigned short*)take((size_t)DM * FFN_D * 2);
    unsigned short* XN    = (unsigned short*)take((size_t)MTOK * DM * 2);
    float* PROJ  = (float*)take((size_t)MTOK * NPROJ * 4);
    float* DECAY = (float*)take((size_t)MTOK * DMAMBA * 4);
    float* INP   = (float*)take((size_t)MTOK * DMAMBA * 4);
    float* CMN   = (float*)take((size_t)MTOK * DST * 4);
    float* PP    = (float*)take((size_t)BSZ * NCH * DMAMBA * 4);
    float* SS    = (float*)take((size_t)BSZ * NCH * DMAMBA * 4);
    float* CARRY = (float*)take((size_t)BSZ * NCH * DMAMBA * 4);
    unsigned short* Y      = (unsigned short*)take((size_t)MTOK * DMAMBA * 2);
    unsigned short* MIXIN  = (unsigned short*)take((size_t)MTOK * DM * 2);
    unsigned short* NORMED = (unsigned short*)take((size_t)MTOK * DM * 2);
    float* MIXER = DECAY;            // overlay: decay/inp dead after scan
    unsigned short* ACT = XN;        // overlay: xn dead after proj gemm
    float* outX = (float*)d_out;
    float* outV = outX + (size_t)MTOK * DM;

    // --- fused weight prep: f32 [K][N] -> bf16 [N][K] ---
    TP tp;
    int tblk = 0;
    auto addT = [&](int i, const float* s, unsigned short* dst, int K, int N) {
        int nb = (K * N + 255) / 256;
        tp.t[i] = TD{s, dst, K, N, nb};
        tblk += nb;
    };
    addT(0, conv_in_w, WCAT, DM, DM);
    addT(1, x_proj_w, WCAT + 512 * DM, DM, DMAMBA);
    addT(2, dt_w, WCAT + 768 * DM, DM, DMAMBA);
    addT(3, B_w, WCAT + 1024 * DM, DM, DST);
    addT(4, C_w, WCAT + 1088 * DM, DM, DST);
    addT(5, ssm_out_w, SSMT, DMAMBA, DMAMBA);
    addT(6, out_proj_w, OUTPT, DM, DM);
    addT(7, w1, W1T, DM, FFN_D);
    addT(8, w3, W3T, DM, FFN_D);
    addT(9, w2, W2T, FFN_D, DM);
    transpose_all_k<<<tblk, 256, 0, stream>>>(tp);

    // --- pipeline ---
    rmsnorm1_k<<<MTOK / 4, 256, 0, stream>>>(x, pre_norm_w, XN);

    gemm_nt<0><<<dim3(NPROJ / 128, MTOK / 128), 256, 0, stream>>>(
        XN, WCAT, nullptr, PROJ, nullptr, DM, NPROJ);

    mamba_prep_k<<<MTOK / 4, 256, 0, stream>>>(PROJ, dt_b, A_log, conv_dw_w, conv_dw_b,
                                               DECAY, INP, CMN, MIXIN);

    scan_chunk_k<<<BSZ * NCH, 256, 0, stream>>>(DECAY, INP, PP, SS);
    scan_prefix_k<<<BSZ, 256, 0, stream>>>(PP, SS, CARRY);
    scan_finish_k<<<BSZ * NCH, 256, 0, stream>>>(DECAY, INP, CARRY, CMN, Dw, PROJ, Y);

    // N = DMAMBA here (R2 bug was DM/128 -> clobbered MIXIN conv half)
    gemm_nt<1><<<dim3(DMAMBA / 128, MTOK / 128), 256, 0, stream>>>(
        Y, SSMT, nullptr, (void*)(MIXIN + 256), nullptr, DMAMBA, DM);

    gemm_nt<0><<<dim3(DM / 128, MTOK / 128), 256, 0, stream>>>(
        MIXIN, OUTPT, nullptr, MIXER, nullptr, DM, DM);

    update_norm_k<<<MTOK / 4, 256, 0, stream>>>(x, velocity, MIXER, log_beta, ffn_norm_w,
                                                outX, outV, NORMED);

    gemm_nt<2><<<dim3(FFN_D / 128, MTOK / 128), 256, 0, stream>>>(
        NORMED, W1T, W3T, ACT, nullptr, DM, FFN_D);

    gemm_nt<3><<<dim3(DM / 128, MTOK / 128), 256, 0, stream>>>(
        ACT, W2T, nullptr, (void*)outX, (const float*)outX, FFN_D, DM);
}

// Round 4
// 883.620 us; speedup vs baseline: 1.1820x; 1.1337x over previous
//
#include <hip/hip_runtime.h>

#define MTOK   32768   // B*L
#define LSEQ   4096
#define BSZ    8
#define DM     512
#define DC     256
#define DMAMBA 256
#define DST    64
#define NPROJ  1152    // 512 uv | 256 x_ssm | 256 dt | 64 B | 64 C
#define FFN_D  2048
#define NCH    64      // scan chunks per sequence
#define CLEN   64      // 4096/64

typedef __attribute__((ext_vector_type(4))) float          f32x4;
typedef __attribute__((ext_vector_type(8))) unsigned short u16x8;
typedef __attribute__((ext_vector_type(8))) __bf16         bf16x8;

typedef const __attribute__((address_space(1))) unsigned int* gptr_t;
typedef __attribute__((address_space(3))) unsigned int*       lptr_t;

static __device__ __forceinline__ unsigned short f2bf(float f) {
    unsigned int u = __builtin_bit_cast(unsigned int, f);
    u += 0x7fffu + ((u >> 16) & 1u);   // RNE
    return (unsigned short)(u >> 16);
}

static __device__ __forceinline__ float wred(float s) {
#pragma unroll
    for (int m = 1; m < 64; m <<= 1) s += __shfl_xor(s, m);
    return s;
}

static __device__ __forceinline__ f32x4 mfma16(u16x8 a, u16x8 b, f32x4 c) {
    return __builtin_amdgcn_mfma_f32_16x16x32_bf16(
        __builtin_bit_cast(bf16x8, a), __builtin_bit_cast(bf16x8, b), c, 0, 0, 0);
}

// async global->LDS, 16B per lane, dest = wave-uniform base + lane*16
static __device__ __forceinline__ void gl16(const unsigned short* g, unsigned short* l) {
    __builtin_amdgcn_global_load_lds((gptr_t)g, (lptr_t)l, 16, 0, 0);
}

// ---------------------------------------------------------------------------
// NT GEMM, 2-phase double-buffered (T3-minimum): C[M][N] = A * Bt^T, bf16->f32.
// 128x128 tile, BK=32, 4 waves (2x2). Per iter: STAGE(next buf) issued BEFORE
// compute(cur buf); single __syncthreads per iter (its vmcnt(0)+barrier both
// drains the prefetch and protects buffer reuse):
//   iter t: write buf[cur^1], read buf[cur]  -> disjoint
//   barrier => all reads of buf[cur] done AND buf[cur^1] fully written
//   iter t+1: roles swap -> safe.
// Grid: (N/128, M/128)  -- blockIdx.x over N so consecutive blocks share A-tile.
// EPI 0: f32 out. 1: bf16 out. 2: dual-B, out = bf16(silu(AB1)*AB2).
// EPI 3: f32 out = Cin + AB  (residual add).
// ---------------------------------------------------------------------------
template <int EPI>
__global__ __launch_bounds__(256) void gemm_nt(
    const unsigned short* __restrict__ A, const unsigned short* __restrict__ Bt,
    const unsigned short* __restrict__ B2t, void* __restrict__ Cp,
    const float* __restrict__ Cin, int K, int ldc)
{
    __shared__ unsigned short As[2 * 128 * 32];
    __shared__ unsigned short Bs[2 * 128 * 32];
    __shared__ unsigned short Bs2[(EPI == 2) ? 2 * 128 * 32 : 8];

    const int tid = threadIdx.x;
    const int lane = tid & 63, wid = tid >> 6;
    const int wr = wid >> 1, wc = wid & 1;
    const long n0 = (long)blockIdx.x * 128;
    const long m0 = (long)blockIdx.y * 128;

    f32x4 acc[4][4], acc2[4][4];
#pragma unroll
    for (int i = 0; i < 4; i++)
#pragma unroll
        for (int j = 0; j < 4; j++) {
            acc[i][j] = f32x4{0.f, 0.f, 0.f, 0.f};
            acc2[i][j] = f32x4{0.f, 0.f, 0.f, 0.f};
        }

    // staging map: wave w covers LDS rows [w*32, w*32+32); 16B per lane:
    // lane l -> row = w*32 + q*16 + l/4, col = (l&3)*8
    const int srow = wid * 32 + (lane >> 2);
    const int scol = (lane & 3) * 8;
    const unsigned short* agp = A + (m0 + srow) * (long)K + scol;
    const unsigned short* bgp = Bt + (n0 + srow) * (long)K + scol;
    const unsigned short* b2gp = (EPI == 2) ? (B2t + (n0 + srow) * (long)K + scol) : nullptr;
    const long skip = 16 * (long)K;

    const int fr = lane & 15, fo = (lane >> 4) * 8;

    auto STAGE = [&](int buf, int k0) {
        unsigned short* dA = As + buf * 4096 + wid * 1024;
        unsigned short* dB = Bs + buf * 4096 + wid * 1024;
        gl16(agp + k0, dA);
        gl16(agp + k0 + skip, dA + 512);
        gl16(bgp + k0, dB);
        gl16(bgp + k0 + skip, dB + 512);
        if constexpr (EPI == 2) {
            unsigned short* dB2 = Bs2 + buf * 4096 + wid * 1024;
            gl16(b2gp + k0, dB2);
            gl16(b2gp + k0 + skip, dB2 + 512);
        }
    };

    auto COMPUTE = [&](int buf) {
        const unsigned short* sA = As + buf * 4096;
        const unsigned short* sB = Bs + buf * 4096;
        u16x8 av[4], bv[4], cv[4];
#pragma unroll
        for (int i = 0; i < 4; i++)
            av[i] = *(const u16x8*)(sA + (wr * 64 + i * 16 + fr) * 32 + fo);
#pragma unroll
        for (int j = 0; j < 4; j++)
            bv[j] = *(const u16x8*)(sB + (wc * 64 + j * 16 + fr) * 32 + fo);
        if constexpr (EPI == 2) {
            const unsigned short* sB2 = Bs2 + buf * 4096;
#pragma unroll
            for (int j = 0; j < 4; j++)
                cv[j] = *(const u16x8*)(sB2 + (wc * 64 + j * 16 + fr) * 32 + fo);
        }
#pragma unroll
        for (int i = 0; i < 4; i++)
#pragma unroll
            for (int j = 0; j < 4; j++) {
                acc[i][j] = mfma16(av[i], bv[j], acc[i][j]);
                if constexpr (EPI == 2) acc2[i][j] = mfma16(av[i], cv[j], acc2[i][j]);
            }
    };

    STAGE(0, 0);
    __syncthreads();            // buf0 ready
    int cur = 0;
    for (int k0 = 32; k0 < K; k0 += 32) {
        STAGE(cur ^ 1, k0);     // prefetch next tile (latency hides under compute)
        COMPUTE(cur);
        __syncthreads();        // drain prefetch + protect buffer swap
        cur ^= 1;
    }
    COMPUTE(cur);               // last tile

    // C/D layout (verified): col = lane&15, row = (lane>>4)*4 + reg
    const int frow = (lane >> 4) * 4;
#pragma unroll
    for (int i = 0; i < 4; i++)
#pragma unroll
        for (int j = 0; j < 4; j++)
#pragma unroll
            for (int r = 0; r < 4; r++) {
                long row = m0 + wr * 64 + i * 16 + frow + r;
                long col = n0 + wc * 64 + j * 16 + fr;
                long idx = row * (long)ldc + col;
                float v = acc[i][j][r];
                if constexpr (EPI == 0) {
                    ((float*)Cp)[idx] = v;
                } else if constexpr (EPI == 1) {
                    ((unsigned short*)Cp)[idx] = f2bf(v);
                } else if constexpr (EPI == 2) {
                    float h3 = acc2[i][j][r];
                    float s = v / (1.f + __expf(-v));
                    ((unsigned short*)Cp)[idx] = f2bf(s * h3);
                } else {
                    ((float*)Cp)[idx] = Cin[idx] + v;
                }
            }
}

// ---------------------------------------------------------------------------
// All weight transposes fused: src[K][N] (f32) -> dst[N][K] (bf16), 10 tables
// ---------------------------------------------------------------------------
struct TD { const float* s; unsigned short* d; int K, N, nb; };
struct TP { TD t[10]; };

__global__ __launch_bounds__(256) void transpose_all_k(TP p)
{
    int b = blockIdx.x;
#pragma unroll
    for (int i = 0; i < 10; i++) {
        TD td = p.t[i];
        if (b < td.nb) {
            int idx = b * 256 + threadIdx.x;
            if (idx < td.K * td.N) {
                int k = idx / td.N, n = idx - k * td.N;
                td.d[(long)n * td.K + k] = f2bf(td.s[idx]);
            }
            return;
        }
        b -= td.nb;
    }
}

// ---------------------------------------------------------------------------
// RMSNorm(x) * w -> bf16. One wave per token (512 elems, 8/lane).
// ---------------------------------------------------------------------------
__global__ __launch_bounds__(256) void rmsnorm1_k(const float* __restrict__ x,
                                                  const float* __restrict__ w,
                                                  unsigned short* __restrict__ out)
{
    const int lane = threadIdx.x & 63, wv = threadIdx.x >> 6;
    const long tok = (long)blockIdx.x * 4 + wv;
    const float* xr = x + tok * DM;
    float4 v[2];
    float s = 0.f;
#pragma unroll
    for (int j = 0; j < 2; j++) {
        int d0 = j * 256 + lane * 4;
        v[j] = *(const float4*)(xr + d0);
        s += v[j].x * v[j].x + v[j].y * v[j].y + v[j].z * v[j].z + v[j].w * v[j].w;
    }
    s = wred(s);
    float r = rsqrtf(s * (1.f / DM) + 1e-6f);
#pragma unroll
    for (int j = 0; j < 2; j++) {
        int d0 = j * 256 + lane * 4;
        const float4 ww = *(const float4*)(w + d0);
        *(ushort4*)(out + tok * DM + d0) = make_ushort4(
            f2bf(v[j].x * r * ww.x), f2bf(v[j].y * r * ww.y),
            f2bf(v[j].z * r * ww.z), f2bf(v[j].w * r * ww.w));
    }
}

// ---------------------------------------------------------------------------
// Per-token mamba prep. One wave per token.
// proj row: [0,512)=uv  [512,768)=x_ssm  [768,1024)=dt_raw  [1024,1088)=B  [1088,1152)=C
// ---------------------------------------------------------------------------
__global__ __launch_bounds__(256) void mamba_prep_k(
    const float* __restrict__ proj, const float* __restrict__ dt_b,
    const float* __restrict__ A_log, const float* __restrict__ conv_w,
    const float* __restrict__ conv_b,
    float* __restrict__ decay, float* __restrict__ inp, float* __restrict__ cmn,
    unsigned short* __restrict__ mixin)
{
    const int lane = threadIdx.x & 63, wv = threadIdx.x >> 6;
    const long tok = (long)blockIdx.x * 4 + wv;
    const int l = (int)(tok & (LSEQ - 1));
    const float* pr = proj + tok * NPROJ;

    float bv = pr[1024 + lane];
    float cv = pr[1088 + lane];
    float nb2 = wred(bv * bv);
    float nc2 = wred(cv * cv);
    float rb = 1.f / fmaxf(sqrtf(nb2), 1.f);
    float rc = 1.f / fmaxf(sqrtf(nc2), 1.f);
    float bn = bv * rb;
    cmn[tok * DST + lane] = cv * rc;

#pragma unroll
    for (int j = 0; j < 4; j++) {
        int d = j * 64 + lane;          // d%64 == lane  -> Bfull[d] = bn
        float dtr = pr[768 + d] + dt_b[d];
        dtr = fminf(fmaxf(dtr, -10.f), 5.f);
        float sp = log1pf(__expf(dtr));
        float dt = fminf(fmaxf(sp, 1e-4f), 0.1f);
        float a = -__expf(A_log[d]);
        decay[tok * DMAMBA + d] = __expf(dt * a);
        inp[tok * DMAMBA + d] = dt * bn * pr[512 + d];

        float ul  = pr[d];
        float um1 = (l >= 1) ? pr[d - NPROJ] : 0.f;
        float um2 = (l >= 2) ? pr[d - 2 * NPROJ] : 0.f;
        float conv = conv_b[d] + um2 * conv_w[d * 3] + um1 * conv_w[d * 3 + 1] + ul * conv_w[d * 3 + 2];
        float g = pr[256 + d];
        float sg = g / (1.f + __expf(-g));
        mixin[tok * DM + d] = f2bf(conv * sg);
    }
}

// ---------------------------------------------------------------------------
// Chunked scan h[l] = decay[l]*h[l-1] + inp[l].
// ---------------------------------------------------------------------------
__global__ __launch_bounds__(256) void scan_chunk_k(const float* __restrict__ decay,
                                                    const float* __restrict__ inp,
                                                    float* __restrict__ P, float* __restrict__ S)
{
    const int bc = blockIdx.x;
    const int b = bc >> 6, c = bc & 63;
    const int d = threadIdx.x;
    long base = ((long)b * LSEQ + (long)c * CLEN) * DMAMBA + d;
    float h = 0.f, p = 1.f;
    for (int t = 0; t < CLEN; t++) {
        float dec = decay[base + (long)t * DMAMBA];
        float iv = inp[base + (long)t * DMAMBA];
        h = dec * h + iv;
        p *= dec;
    }
    P[(long)bc * DMAMBA + d] = p;
    S[(long)bc * DMAMBA + d] = h;
}

__global__ __launch_bounds__(256) void scan_prefix_k(const float* __restrict__ P,
                                                     const float* __restrict__ S,
                                                     float* __restrict__ carry)
{
    const int b = blockIdx.x, d = threadIdx.x;
    float H = 0.f;
    for (int c = 0; c < NCH; c++) {
        long i = ((long)b * NCH + c) * DMAMBA + d;
        carry[i] = H;
        H = P[i] * H + S[i];
    }
}

__global__ __launch_bounds__(256) void scan_finish_k(
    const float* __restrict__ decay, const float* __restrict__ inp,
    const float* __restrict__ carry, const float* __restrict__ cmn,
    const float* __restrict__ Dw, const float* __restrict__ proj,
    unsigned short* __restrict__ y)
{
    const int bc = blockIdx.x;
    const int b = bc >> 6, c = bc & 63;
    const int d = threadIdx.x;
    const long tok0 = (long)b * LSEQ + (long)c * CLEN;
    float h = carry[(long)bc * DMAMBA + d];
    const float dv = Dw[d];
    for (int t = 0; t < CLEN; t++) {
        long tok = tok0 + t;
        long idx = tok * DMAMBA + d;
        h = decay[idx] * h + inp[idx];
        float yv = h * cmn[tok * DST + (d & 63)] + dv * proj[tok * NPROJ + 512 + d];
        y[idx] = f2bf(yv);
    }
}

// ---------------------------------------------------------------------------
// velocity/x update + RMSNorm -> normed bf16. One wave per token.
// ---------------------------------------------------------------------------
__global__ __launch_bounds__(256) void update_norm_k(
    const float* __restrict__ x, const float* __restrict__ vel,
    const float* __restrict__ mixer, const float* __restrict__ lbeta,
    const float* __restrict__ fw, float* __restrict__ outX,
    float* __restrict__ outV, unsigned short* __restrict__ normed)
{
    const int lane = threadIdx.x & 63, wv = threadIdx.x >> 6;
    const long tok = (long)blockIdx.x * 4 + wv;
    const float beta = 1.f / (1.f + __expf(-lbeta[0]));
    float xs[8];
    float s = 0.f;
#pragma unroll
    for (int j = 0; j < 2; j++) {
        const int d0 = j * 256 + lane * 4;
        const float4 xv = *(const float4*)(x + tok * DM + d0);
        const float4 vv = *(const float4*)(vel + tok * DM + d0);
        const float4 mv = *(const float4*)(mixer + tok * DM + d0);
        float4 vn, xn;
        vn.x = beta * vv.x + mv.x; xn.x = xv.x + vn.x;
        vn.y = beta * vv.y + mv.y; xn.y = xv.y + vn.y;
        vn.z = beta * vv.z + mv.z; xn.z = xv.z + vn.z;
        vn.w = beta * vv.w + mv.w; xn.w = xv.w + vn.w;
        *(float4*)(outV + tok * DM + d0) = vn;
        *(float4*)(outX + tok * DM + d0) = xn;
        s += xn.x * xn.x + xn.y * xn.y + xn.z * xn.z + xn.w * xn.w;
        xs[j * 4 + 0] = xn.x; xs[j * 4 + 1] = xn.y; xs[j * 4 + 2] = xn.z; xs[j * 4 + 3] = xn.w;
    }
    s = wred(s);
    const float r = rsqrtf(s * (1.f / DM) + 1e-6f);
#pragma unroll
    for (int j = 0; j < 2; j++) {
        const int d0 = j * 256 + lane * 4;
        const float4 ww = *(const float4*)(fw + d0);
        *(ushort4*)(normed + tok * DM + d0) = make_ushort4(
            f2bf(xs[j * 4 + 0] * r * ww.x), f2bf(xs[j * 4 + 1] * r * ww.y),
            f2bf(xs[j * 4 + 2] * r * ww.z), f2bf(xs[j * 4 + 3] * r * ww.w));
    }
}

// ---------------------------------------------------------------------------
extern "C" void kernel_launch(void* const* d_in, const int* in_sizes, int n_in,
                              void* d_out, int out_size, void* d_ws, size_t ws_size,
                              hipStream_t stream)
{
    (void)in_sizes; (void)n_in; (void)out_size; (void)ws_size;

    const float* x          = (const float*)d_in[0];
    const float* velocity   = (const float*)d_in[1];
    const float* pre_norm_w = (const float*)d_in[2];
    const float* conv_in_w  = (const float*)d_in[3];
    const float* conv_dw_w  = (const float*)d_in[4];
    const float* conv_dw_b  = (const float*)d_in[5];
    const float* x_proj_w   = (const float*)d_in[6];
    const float* dt_w       = (const float*)d_in[7];
    const float* dt_b       = (const float*)d_in[8];
    const float* B_w        = (const float*)d_in[9];
    const float* C_w        = (const float*)d_in[10];
    const float* A_log      = (const float*)d_in[11];
    const float* Dw         = (const float*)d_in[12];
    const float* ssm_out_w  = (const float*)d_in[13];
    const float* out_proj_w = (const float*)d_in[14];
    const float* log_beta   = (const float*)d_in[15];
    const float* ffn_norm_w = (const float*)d_in[16];
    const float* w1         = (const float*)d_in[17];
    const float* w3         = (const float*)d_in[18];
    const float* w2         = (const float*)d_in[19];

    char* base = (char*)d_ws;
    size_t off = 0;
    auto take = [&](size_t bytes) -> void* {
        void* p = base + off;
        off = (off + bytes + 255) & ~(size_t)255;
        return p;
    };
    unsigned short* WCAT  = (unsigned short*)take((size_t)NPROJ * DM * 2);
    unsigned short* SSMT  = (unsigned short*)take((size_t)DMAMBA * DMAMBA * 2);
    unsigned short* OUTPT = (unsigned short*)take((size_t)DM * DM * 2);
    unsigned short* W1T   = (unsigned short*)take((size_t)FFN_D * DM * 2);
    unsigned short* W3T   = (unsigned short*)take((size_t)FFN_D * DM * 2);
    unsigned short* W2T   = (unsigned short*)take((size_t)DM * FFN_D * 2);
    unsigned short* XN    = (unsigned short*)take((size_t)MTOK * DM * 2);
    float* PROJ  = (float*)take((size_t)MTOK * NPROJ * 4);
    float* DECAY = (float*)take((size_t)MTOK * DMAMBA * 4);
    float* INP   = (float*)take((size_t)MTOK * DMAMBA * 4);
    float* CMN   = (float*)take((size_t)MTOK * DST * 4);
    float* PP    = (float*)take((size_t)BSZ * NCH * DMAMBA * 4);
    float* SS    = (float*)take((size_t)BSZ * NCH * DMAMBA * 4);
    float* CARRY = (float*)take((size_t)BSZ * NCH * DMAMBA * 4);
    unsigned short* Y      = (unsigned short*)take((size_t)MTOK * DMAMBA * 2);
    unsigned short* MIXIN  = (unsigned short*)take((size_t)MTOK * DM * 2);
    unsigned short* NORMED = (unsigned short*)take((size_t)MTOK * DM * 2);
    float* MIXER = DECAY;            // overlay: decay/inp dead after scan
    unsigned short* ACT = XN;        // overlay: xn dead after proj gemm
    float* outX = (float*)d_out;
    float* outV = outX + (size_t)MTOK * DM;

    // --- fused weight prep: f32 [K][N] -> bf16 [N][K] ---
    TP tp;
    int tblk = 0;
    auto addT = [&](int i, const float* s, unsigned short* dst, int K, int N) {
        int nb = (K * N + 255) / 256;
        tp.t[i] = TD{s, dst, K, N, nb};
        tblk += nb;
    };
    addT(0, conv_in_w, WCAT, DM, DM);
    addT(1, x_proj_w, WCAT + 512 * DM, DM, DMAMBA);
    addT(2, dt_w, WCAT + 768 * DM, DM, DMAMBA);
    addT(3, B_w, WCAT + 1024 * DM, DM, DST);
    addT(4, C_w, WCAT + 1088 * DM, DM, DST);
    addT(5, ssm_out_w, SSMT, DMAMBA, DMAMBA);
    addT(6, out_proj_w, OUTPT, DM, DM);
    addT(7, w1, W1T, DM, FFN_D);
    addT(8, w3, W3T, DM, FFN_D);
    addT(9, w2, W2T, FFN_D, DM);
    transpose_all_k<<<tblk, 256, 0, stream>>>(tp);

    // --- pipeline ---
    rmsnorm1_k<<<MTOK / 4, 256, 0, stream>>>(x, pre_norm_w, XN);

    gemm_nt<0><<<dim3(NPROJ / 128, MTOK / 128), 256, 0, stream>>>(
        XN, WCAT, nullptr, PROJ, nullptr, DM, NPROJ);

    mamba_prep_k<<<MTOK / 4, 256, 0, stream>>>(PROJ, dt_b, A_log, conv_dw_w, conv_dw_b,
                                               DECAY, INP, CMN, MIXIN);

    scan_chunk_k<<<BSZ * NCH, 256, 0, stream>>>(DECAY, INP, PP, SS);
    scan_prefix_k<<<BSZ, 256, 0, stream>>>(PP, SS, CARRY);
    scan_finish_k<<<BSZ * NCH, 256, 0, stream>>>(DECAY, INP, CARRY, CMN, Dw, PROJ, Y);

    // N = DMAMBA (grid.x = 2)
    gemm_nt<1><<<dim3(DMAMBA / 128, MTOK / 128), 256, 0, stream>>>(
        Y, SSMT, nullptr, (void*)(MIXIN + 256), nullptr, DMAMBA, DM);

    gemm_nt<0><<<dim3(DM / 128, MTOK / 128), 256, 0, stream>>>(
        MIXIN, OUTPT, nullptr, MIXER, nullptr, DM, DM);

    update_norm_k<<<MTOK / 4, 256, 0, stream>>>(x, velocity, MIXER, log_beta, ffn_norm_w,
                                                outX, outV, NORMED);

    gemm_nt<2><<<dim3(FFN_D / 128, MTOK / 128), 256, 0, stream>>>(
        NORMED, W1T, W3T, ACT, nullptr, DM, FFN_D);

    gemm_nt<3><<<dim3(DM / 128, MTOK / 128), 256, 0, stream>>>(
        ACT, W2T, nullptr, (void*)outX, (const float*)outX, FFN_D, DM);
}

// Round 5
// 827.352 us; speedup vs baseline: 1.2624x; 1.0680x over previous
//
#include <hip/hip_runtime.h>

#define MTOK   32768   // B*L
#define LSEQ   4096
#define BSZ    8
#define DM     512
#define DC     256
#define DMAMBA 256
#define DST    64
#define NPROJ  1152    // 512 uv | 256 x_ssm | 256 dt | 64 B | 64 C
#define NPROJP 1280    // padded to 5x256 for the 256-tile GEMM
#define FFN_D  2048
#define NCH    64      // scan chunks per sequence
#define CLEN   64      // 4096/64

typedef __attribute__((ext_vector_type(4))) float          f32x4;
typedef __attribute__((ext_vector_type(8))) unsigned short u16x8;
typedef __attribute__((ext_vector_type(8))) __bf16         bf16x8;

typedef const __attribute__((address_space(1))) unsigned int* gptr_t;
typedef __attribute__((address_space(3))) unsigned int*       lptr_t;

static __device__ __forceinline__ unsigned short f2bf(float f) {
    unsigned int u = __builtin_bit_cast(unsigned int, f);
    u += 0x7fffu + ((u >> 16) & 1u);   // RNE
    return (unsigned short)(u >> 16);
}

static __device__ __forceinline__ float wred(float s) {
#pragma unroll
    for (int m = 1; m < 64; m <<= 1) s += __shfl_xor(s, m);
    return s;
}

static __device__ __forceinline__ f32x4 mfma16(u16x8 a, u16x8 b, f32x4 c) {
    return __builtin_amdgcn_mfma_f32_16x16x32_bf16(
        __builtin_bit_cast(bf16x8, a), __builtin_bit_cast(bf16x8, b), c, 0, 0, 0);
}

// async global->LDS, 16B per lane, dest = wave-uniform base + lane*16
static __device__ __forceinline__ void gl16(const unsigned short* g, unsigned short* l) {
    __builtin_amdgcn_global_load_lds((gptr_t)g, (lptr_t)l, 16, 0, 0);
}

#define VMCNT4 asm volatile("s_waitcnt vmcnt(4)" ::: "memory")
#define VMCNT0 asm volatile("s_waitcnt vmcnt(0)" ::: "memory")
#define LGKM0  do { asm volatile("s_waitcnt lgkmcnt(0)" ::: "memory"); \
                    __builtin_amdgcn_sched_barrier(0); } while (0)

// ---------------------------------------------------------------------------
// gemm256: 256x256 tile, BK=64, 8 waves (2Mx4N), 2-buf LDS, 4 sub-phases/K-tile
// with counted vmcnt (T3+T4), st-swizzle (T2), setprio (T5).
//   A[M][K] (bf16), Bt[N][K] (bf16) -> C[M][N]
// Staging: half-tile (128 rows x 64 cols = 16KB) = 2 gl16/thread. LDS dest is
// LINEAR; swizzle applied by pre-swizzling the per-lane GLOBAL source col and
// XOR-ing the ds_read address (involution closes; m173/m201 pattern).
// Schedule invariants (ring-2 per matrix):
//   sp0: read bv(all)+av(q0) of tile t; stage A(t+1).h0 -> slot^1 (A(t-1) dead)
//   sp1: av q1; stage A(t+1).h1
//   sp2: av q2; stage B(t+2).h0 -> slot (B(t) fully in regs since sp0)
//   sp3: av q3; stage B(t+2).h1; vmcnt(4) [confirms A(t+1),B(t+1); leaves B(t+2)]
// Raw s_barrier x2 per sub-phase; loads cross barriers (never vmcnt(0) mid-loop).
// EPI 0: f32 out. 1: bf16 out. 2: bf16 out = silu(aux[idx])*acc. 3: f32 Cin+acc.
// ---------------------------------------------------------------------------
template <int EPI>
__global__ __launch_bounds__(512) void gemm256(
    const unsigned short* __restrict__ A, const unsigned short* __restrict__ Bt,
    const unsigned short* __restrict__ aux, void* __restrict__ Cp,
    const float* __restrict__ Cin, int K, int ldc)
{
    __shared__ unsigned short As[2 * 256 * 64];   // 64KB (2 slots x 32KB)
    __shared__ unsigned short Bs[2 * 256 * 64];   // 64KB

    const int tid = threadIdx.x;
    const int lane = tid & 63, wid = tid >> 6;
    const int wr = wid >> 2, wcol = wid & 3;      // 2 x 4 wave grid
    const long n0 = (long)blockIdx.x * 256;
    const long m0 = (long)blockIdx.y * 256;
    const int NT = K >> 6;

    f32x4 acc[8][4];
#pragma unroll
    for (int i = 0; i < 8; i++)
#pragma unroll
        for (int j = 0; j < 4; j++) acc[i][j] = f32x4{0.f, 0.f, 0.f, 0.f};

    // staging source (inverse-swizzled): chunk c=wid*2+qq covers rows [c*8,c*8+8)
    const int sr = lane >> 3;                       // row within chunk
    const int scol = ((lane & 7) ^ (lane >> 3)) * 8;  // swizzled col (elems)

    auto stageA = [&](int k0, int half, int sl) {
#pragma unroll
        for (int qq = 0; qq < 2; qq++) {
            int c = wid * 2 + qq;
            const unsigned short* src = A + (m0 + half * 128 + c * 8 + sr) * (long)K + k0 + scol;
            gl16(src, As + sl * 16384 + half * 8192 + c * 512);
        }
    };
    auto stageB = [&](int k0, int half, int sl) {
#pragma unroll
        for (int qq = 0; qq < 2; qq++) {
            int c = wid * 2 + qq;
            const unsigned short* src = Bt + (n0 + half * 128 + c * 8 + sr) * (long)K + k0 + scol;
            gl16(src, Bs + sl * 16384 + half * 8192 + c * 512);
        }
    };

    const int fr = lane & 15;
    const int cB0 = (lane >> 4) * 16;               // colByte for ks=0
    auto ldA = [&](int sl, int row, int cb) -> u16x8 {
        int off = row * 128 + cb;
        off ^= (row & 7) << 4;                       // T2 swizzle
        return *(const u16x8*)((const char*)As + sl * 32768 + off);
    };
    auto ldB = [&](int sl, int row, int cb) -> u16x8 {
        int off = row * 128 + cb;
        off ^= (row & 7) << 4;
        return *(const u16x8*)((const char*)Bs + sl * 32768 + off);
    };

    // prologue: A(0).h0,h1, B(0).h0,h1, B(1).h0,h1  -> vmcnt(4) leaves B(1)
    stageA(0, 0, 0); stageA(0, 1, 0);
    stageB(0, 0, 0); stageB(0, 1, 0);
    if (NT > 1) { stageB(64, 0, 1); stageB(64, 1, 1); VMCNT4; }
    else VMCNT0;
    __builtin_amdgcn_s_barrier();

    int slot = 0;
    for (int t = 0; t < NT; ++t) {
        const int kN = (t + 1) << 6;     // K-offset of tile t+1
        const int kN2 = (t + 2) << 6;    // K-offset of tile t+2
        u16x8 bv[4][2];
#pragma unroll
        for (int q = 0; q < 4; q++) {
            // ds_read this sub-phase's fragments (tile t)
            u16x8 av[2][2];
#pragma unroll
            for (int ii = 0; ii < 2; ii++) {
                int row = wr * 128 + (q * 2 + ii) * 16 + fr;
                av[ii][0] = ldA(slot, row, cB0);
                av[ii][1] = ldA(slot, row, 64 + cB0);
            }
            if (q == 0) {
#pragma unroll
                for (int j = 0; j < 4; j++) {
                    int row = wcol * 64 + j * 16 + fr;
                    bv[j][0] = ldB(slot, row, cB0);
                    bv[j][1] = ldB(slot, row, 64 + cB0);
                }
            }
            // stage one future half-tile (stays in flight across barriers)
            if (q == 0 && t + 1 < NT) stageA(kN, 0, slot ^ 1);
            if (q == 1 && t + 1 < NT) stageA(kN, 1, slot ^ 1);
            if (q == 2 && t + 2 < NT) stageB(kN2, 0, slot);
            if (q == 3 && t + 2 < NT) stageB(kN2, 1, slot);

            __builtin_amdgcn_s_barrier();
            LGKM0;
            __builtin_amdgcn_s_setprio(1);
#pragma unroll
            for (int ii = 0; ii < 2; ii++)
#pragma unroll
                for (int j = 0; j < 4; j++) {
                    acc[q * 2 + ii][j] = mfma16(av[ii][0], bv[j][0], acc[q * 2 + ii][j]);
                    acc[q * 2 + ii][j] = mfma16(av[ii][1], bv[j][1], acc[q * 2 + ii][j]);
                }
            __builtin_amdgcn_s_setprio(0);
            if (q == 3 && t + 1 < NT) {
                if (t + 2 < NT) VMCNT4;   // confirm A(t+1)+B(t+1); leave B(t+2)
                else VMCNT0;              // tail: nothing newer to protect
            }
            __builtin_amdgcn_s_barrier();
        }
        slot ^= 1;
    }

    // C/D layout (verified): col = lane&15, row = (lane>>4)*4 + reg
    const int frow = (lane >> 4) * 4;
#pragma unroll
    for (int i = 0; i < 8; i++)
#pragma unroll
        for (int j = 0; j < 4; j++)
#pragma unroll
            for (int r = 0; r < 4; r++) {
                long row = m0 + wr * 128 + i * 16 + frow + r;
                long col = n0 + wcol * 64 + j * 16 + fr;
                long idx = row * (long)ldc + col;
                float v = acc[i][j][r];
                if constexpr (EPI == 0) {
                    ((float*)Cp)[idx] = v;
                } else if constexpr (EPI == 1) {
                    ((unsigned short*)Cp)[idx] = f2bf(v);
                } else if constexpr (EPI == 2) {
                    unsigned int u = (unsigned int)((const unsigned short*)aux)[idx] << 16;
                    float h = __builtin_bit_cast(float, u);
                    float s = h / (1.f + __expf(-h));
                    ((unsigned short*)Cp)[idx] = f2bf(s * v);
                } else {
                    ((float*)Cp)[idx] = Cin[idx] + v;
                }
            }
}

// ---------------------------------------------------------------------------
// Old 128x128 2-phase NT GEMM — retained for ssm_out (N=256, K=256: too small
// for the 256-tile engine's grid). EPI 1: bf16 out.
// ---------------------------------------------------------------------------
template <int EPI>
__global__ __launch_bounds__(256) void gemm_nt(
    const unsigned short* __restrict__ A, const unsigned short* __restrict__ Bt,
    void* __restrict__ Cp, int K, int ldc)
{
    __shared__ unsigned short As[2 * 128 * 32];
    __shared__ unsigned short Bs[2 * 128 * 32];

    const int tid = threadIdx.x;
    const int lane = tid & 63, wid = tid >> 6;
    const int wr = wid >> 1, wc = wid & 1;
    const long n0 = (long)blockIdx.x * 128;
    const long m0 = (long)blockIdx.y * 128;

    f32x4 acc[4][4];
#pragma unroll
    for (int i = 0; i < 4; i++)
#pragma unroll
        for (int j = 0; j < 4; j++) acc[i][j] = f32x4{0.f, 0.f, 0.f, 0.f};

    const int srow = wid * 32 + (lane >> 2);
    const int scol = (lane & 3) * 8;
    const unsigned short* agp = A + (m0 + srow) * (long)K + scol;
    const unsigned short* bgp = Bt + (n0 + srow) * (long)K + scol;
    const long skip = 16 * (long)K;
    const int fr = lane & 15, fo = (lane >> 4) * 8;

    auto STAGE = [&](int buf, int k0) {
        unsigned short* dA = As + buf * 4096 + wid * 1024;
        unsigned short* dB = Bs + buf * 4096 + wid * 1024;
        gl16(agp + k0, dA);
        gl16(agp + k0 + skip, dA + 512);
        gl16(bgp + k0, dB);
        gl16(bgp + k0 + skip, dB + 512);
    };
    auto COMPUTE = [&](int buf) {
        const unsigned short* sA = As + buf * 4096;
        const unsigned short* sB = Bs + buf * 4096;
        u16x8 av[4], bv[4];
#pragma unroll
        for (int i = 0; i < 4; i++)
            av[i] = *(const u16x8*)(sA + (wr * 64 + i * 16 + fr) * 32 + fo);
#pragma unroll
        for (int j = 0; j < 4; j++)
            bv[j] = *(const u16x8*)(sB + (wc * 64 + j * 16 + fr) * 32 + fo);
#pragma unroll
        for (int i = 0; i < 4; i++)
#pragma unroll
            for (int j = 0; j < 4; j++)
                acc[i][j] = mfma16(av[i], bv[j], acc[i][j]);
    };

    STAGE(0, 0);
    __syncthreads();
    int cur = 0;
    for (int k0 = 32; k0 < K; k0 += 32) {
        STAGE(cur ^ 1, k0);
        COMPUTE(cur);
        __syncthreads();
        cur ^= 1;
    }
    COMPUTE(cur);

    const int frow = (lane >> 4) * 4;
#pragma unroll
    for (int i = 0; i < 4; i++)
#pragma unroll
        for (int j = 0; j < 4; j++)
#pragma unroll
            for (int r = 0; r < 4; r++) {
                long row = m0 + wr * 64 + i * 16 + frow + r;
                long col = n0 + wc * 64 + j * 16 + fr;
                long idx = row * (long)ldc + col;
                ((unsigned short*)Cp)[idx] = f2bf(acc[i][j][r]);
            }
}

// ---------------------------------------------------------------------------
// Weight transposes fused: src[K][N] (f32) -> dst[N][K] (bf16); s==null => 0-fill
// ---------------------------------------------------------------------------
struct TD { const float* s; unsigned short* d; int K, N, nb; };
struct TP { TD t[11]; };

__global__ __launch_bounds__(256) void transpose_all_k(TP p)
{
    int b = blockIdx.x;
#pragma unroll
    for (int i = 0; i < 11; i++) {
        TD td = p.t[i];
        if (b < td.nb) {
            int idx = b * 256 + threadIdx.x;
            if (idx < td.K * td.N) {
                if (td.s == nullptr) {
                    td.d[idx] = 0;
                } else {
                    int k = idx / td.N, n = idx - k * td.N;
                    td.d[(long)n * td.K + k] = f2bf(td.s[idx]);
                }
            }
            return;
        }
        b -= td.nb;
    }
}

// ---------------------------------------------------------------------------
// RMSNorm(x) * w -> bf16. One wave per token (512 elems, 8/lane).
// ---------------------------------------------------------------------------
__global__ __launch_bounds__(256) void rmsnorm1_k(const float* __restrict__ x,
                                                  const float* __restrict__ w,
                                                  unsigned short* __restrict__ out)
{
    const int lane = threadIdx.x & 63, wv = threadIdx.x >> 6;
    const long tok = (long)blockIdx.x * 4 + wv;
    const float* xr = x + tok * DM;
    float4 v[2];
    float s = 0.f;
#pragma unroll
    for (int j = 0; j < 2; j++) {
        int d0 = j * 256 + lane * 4;
        v[j] = *(const float4*)(xr + d0);
        s += v[j].x * v[j].x + v[j].y * v[j].y + v[j].z * v[j].z + v[j].w * v[j].w;
    }
    s = wred(s);
    float r = rsqrtf(s * (1.f / DM) + 1e-6f);
#pragma unroll
    for (int j = 0; j < 2; j++) {
        int d0 = j * 256 + lane * 4;
        const float4 ww = *(const float4*)(w + d0);
        *(ushort4*)(out + tok * DM + d0) = make_ushort4(
            f2bf(v[j].x * r * ww.x), f2bf(v[j].y * r * ww.y),
            f2bf(v[j].z * r * ww.z), f2bf(v[j].w * r * ww.w));
    }
}

// ---------------------------------------------------------------------------
// Per-token mamba prep. One wave per token. proj row stride NPROJP.
// layout: [0,512)=uv [512,768)=x_ssm [768,1024)=dt_raw [1024,1088)=B [1088,1152)=C
// ---------------------------------------------------------------------------
__global__ __launch_bounds__(256) void mamba_prep_k(
    const float* __restrict__ proj, const float* __restrict__ dt_b,
    const float* __restrict__ A_log, const float* __restrict__ conv_w,
    const float* __restrict__ conv_b,
    float* __restrict__ decay, float* __restrict__ inp, float* __restrict__ cmn,
    unsigned short* __restrict__ mixin)
{
    const int lane = threadIdx.x & 63, wv = threadIdx.x >> 6;
    const long tok = (long)blockIdx.x * 4 + wv;
    const int l = (int)(tok & (LSEQ - 1));
    const float* pr = proj + tok * NPROJP;

    float bv = pr[1024 + lane];
    float cv = pr[1088 + lane];
    float nb2 = wred(bv * bv);
    float nc2 = wred(cv * cv);
    float rb = 1.f / fmaxf(sqrtf(nb2), 1.f);
    float rc = 1.f / fmaxf(sqrtf(nc2), 1.f);
    float bn = bv * rb;
    cmn[tok * DST + lane] = cv * rc;

#pragma unroll
    for (int j = 0; j < 4; j++) {
        int d = j * 64 + lane;          // d%64 == lane  -> Bfull[d] = bn
        float dtr = pr[768 + d] + dt_b[d];
        dtr = fminf(fmaxf(dtr, -10.f), 5.f);
        float sp = log1pf(__expf(dtr));
        float dt = fminf(fmaxf(sp, 1e-4f), 0.1f);
        float a = -__expf(A_log[d]);
        decay[tok * DMAMBA + d] = __expf(dt * a);
        inp[tok * DMAMBA + d] = dt * bn * pr[512 + d];

        float ul  = pr[d];
        float um1 = (l >= 1) ? pr[d - NPROJP] : 0.f;
        float um2 = (l >= 2) ? pr[d - 2 * NPROJP] : 0.f;
        float conv = conv_b[d] + um2 * conv_w[d * 3] + um1 * conv_w[d * 3 + 1] + ul * conv_w[d * 3 + 2];
        float g = pr[256 + d];
        float sg = g / (1.f + __expf(-g));
        mixin[tok * DM + d] = f2bf(conv * sg);
    }
}

// ---------------------------------------------------------------------------
// Chunked scan h[l] = decay[l]*h[l-1] + inp[l].
// ---------------------------------------------------------------------------
__global__ __launch_bounds__(256) void scan_chunk_k(const float* __restrict__ decay,
                                                    const float* __restrict__ inp,
                                                    float* __restrict__ P, float* __restrict__ S)
{
    const int bc = blockIdx.x;
    const int b = bc >> 6, c = bc & 63;
    const int d = threadIdx.x;
    long base = ((long)b * LSEQ + (long)c * CLEN) * DMAMBA + d;
    float h = 0.f, p = 1.f;
    for (int t = 0; t < CLEN; t++) {
        float dec = decay[base + (long)t * DMAMBA];
        float iv = inp[base + (long)t * DMAMBA];
        h = dec * h + iv;
        p *= dec;
    }
    P[(long)bc * DMAMBA + d] = p;
    S[(long)bc * DMAMBA + d] = h;
}

__global__ __launch_bounds__(256) void scan_prefix_k(const float* __restrict__ P,
                                                     const float* __restrict__ S,
                                                     float* __restrict__ carry)
{
    const int b = blockIdx.x, d = threadIdx.x;
    float H = 0.f;
    for (int c = 0; c < NCH; c++) {
        long i = ((long)b * NCH + c) * DMAMBA + d;
        carry[i] = H;
        H = P[i] * H + S[i];
    }
}

__global__ __launch_bounds__(256) void scan_finish_k(
    const float* __restrict__ decay, const float* __restrict__ inp,
    const float* __restrict__ carry, const float* __restrict__ cmn,
    const float* __restrict__ Dw, const float* __restrict__ proj,
    unsigned short* __restrict__ y)
{
    const int bc = blockIdx.x;
    const int b = bc >> 6, c = bc & 63;
    const int d = threadIdx.x;
    const long tok0 = (long)b * LSEQ + (long)c * CLEN;
    float h = carry[(long)bc * DMAMBA + d];
    const float dv = Dw[d];
    for (int t = 0; t < CLEN; t++) {
        long tok = tok0 + t;
        long idx = tok * DMAMBA + d;
        h = decay[idx] * h + inp[idx];
        float yv = h * cmn[tok * DST + (d & 63)] + dv * proj[tok * NPROJP + 512 + d];
        y[idx] = f2bf(yv);
    }
}

// ---------------------------------------------------------------------------
// velocity/x update + RMSNorm -> normed bf16. One wave per token.
// ---------------------------------------------------------------------------
__global__ __launch_bounds__(256) void update_norm_k(
    const float* __restrict__ x, const float* __restrict__ vel,
    const float* __restrict__ mixer, const float* __restrict__ lbeta,
    const float* __restrict__ fw, float* __restrict__ outX,
    float* __restrict__ outV, unsigned short* __restrict__ normed)
{
    const int lane = threadIdx.x & 63, wv = threadIdx.x >> 6;
    const long tok = (long)blockIdx.x * 4 + wv;
    const float beta = 1.f / (1.f + __expf(-lbeta[0]));
    float xs[8];
    float s = 0.f;
#pragma unroll
    for (int j = 0; j < 2; j++) {
        const int d0 = j * 256 + lane * 4;
        const float4 xv = *(const float4*)(x + tok * DM + d0);
        const float4 vv = *(const float4*)(vel + tok * DM + d0);
        const float4 mv = *(const float4*)(mixer + tok * DM + d0);
        float4 vn, xn;
        vn.x = beta * vv.x + mv.x; xn.x = xv.x + vn.x;
        vn.y = beta * vv.y + mv.y; xn.y = xv.y + vn.y;
        vn.z = beta * vv.z + mv.z; xn.z = xv.z + vn.z;
        vn.w = beta * vv.w + mv.w; xn.w = xv.w + vn.w;
        *(float4*)(outV + tok * DM + d0) = vn;
        *(float4*)(outX + tok * DM + d0) = xn;
        s += xn.x * xn.x + xn.y * xn.y + xn.z * xn.z + xn.w * xn.w;
        xs[j * 4 + 0] = xn.x; xs[j * 4 + 1] = xn.y; xs[j * 4 + 2] = xn.z; xs[j * 4 + 3] = xn.w;
    }
    s = wred(s);
    const float r = rsqrtf(s * (1.f / DM) + 1e-6f);
#pragma unroll
    for (int j = 0; j < 2; j++) {
        const int d0 = j * 256 + lane * 4;
        const float4 ww = *(const float4*)(fw + d0);
        *(ushort4*)(normed + tok * DM + d0) = make_ushort4(
            f2bf(xs[j * 4 + 0] * r * ww.x), f2bf(xs[j * 4 + 1] * r * ww.y),
            f2bf(xs[j * 4 + 2] * r * ww.z), f2bf(xs[j * 4 + 3] * r * ww.w));
    }
}

// ---------------------------------------------------------------------------
extern "C" void kernel_launch(void* const* d_in, const int* in_sizes, int n_in,
                              void* d_out, int out_size, void* d_ws, size_t ws_size,
                              hipStream_t stream)
{
    (void)in_sizes; (void)n_in; (void)out_size; (void)ws_size;

    const float* x          = (const float*)d_in[0];
    const float* velocity   = (const float*)d_in[1];
    const float* pre_norm_w = (const float*)d_in[2];
    const float* conv_in_w  = (const float*)d_in[3];
    const float* conv_dw_w  = (const float*)d_in[4];
    const float* conv_dw_b  = (const float*)d_in[5];
    const float* x_proj_w   = (const float*)d_in[6];
    const float* dt_w       = (const float*)d_in[7];
    const float* dt_b       = (const float*)d_in[8];
    const float* B_w        = (const float*)d_in[9];
    const float* C_w        = (const float*)d_in[10];
    const float* A_log      = (const float*)d_in[11];
    const float* Dw         = (const float*)d_in[12];
    const float* ssm_out_w  = (const float*)d_in[13];
    const float* out_proj_w = (const float*)d_in[14];
    const float* log_beta   = (const float*)d_in[15];
    const float* ffn_norm_w = (const float*)d_in[16];
    const float* w1         = (const float*)d_in[17];
    const float* w3         = (const float*)d_in[18];
    const float* w2         = (const float*)d_in[19];

    char* base = (char*)d_ws;
    size_t off = 0;
    auto take = [&](size_t bytes) -> void* {
        void* p = base + off;
        off = (off + bytes + 255) & ~(size_t)255;
        return p;
    };
    unsigned short* WCAT  = (unsigned short*)take((size_t)NPROJP * DM * 2);  // 1280 rows (pad zeroed)
    unsigned short* SSMT  = (unsigned short*)take((size_t)DMAMBA * DMAMBA * 2);
    unsigned short* OUTPT = (unsigned short*)take((size_t)DM * DM * 2);
    unsigned short* W1T   = (unsigned short*)take((size_t)FFN_D * DM * 2);
    unsigned short* W3T   = (unsigned short*)take((size_t)FFN_D * DM * 2);
    unsigned short* W2T   = (unsigned short*)take((size_t)DM * FFN_D * 2);
    unsigned short* XN    = (unsigned short*)take((size_t)MTOK * DM * 2);
    float* PROJ  = (float*)take((size_t)MTOK * NPROJP * 4);
    float* DECAY = (float*)take((size_t)MTOK * DMAMBA * 4);
    float* INP   = (float*)take((size_t)MTOK * DMAMBA * 4);
    float* CMN   = (float*)take((size_t)MTOK * DST * 4);
    float* PP    = (float*)take((size_t)BSZ * NCH * DMAMBA * 4);
    float* SS    = (float*)take((size_t)BSZ * NCH * DMAMBA * 4);
    float* CARRY = (float*)take((size_t)BSZ * NCH * DMAMBA * 4);
    unsigned short* Y      = (unsigned short*)take((size_t)MTOK * DMAMBA * 2);
    unsigned short* MIXIN  = (unsigned short*)take((size_t)MTOK * DM * 2);
    unsigned short* NORMED = (unsigned short*)take((size_t)MTOK * DM * 2);
    float* MIXER = DECAY;                   // overlay: decay/inp dead after scan
    unsigned short* ACT = XN;               // overlay: xn dead after proj gemm
    unsigned short* H1  = (unsigned short*)PROJ;  // overlay: proj dead after scan_finish (134MB<=168MB)
    float* outX = (float*)d_out;
    float* outV = outX + (size_t)MTOK * DM;

    // --- fused weight prep: f32 [K][N] -> bf16 [N][K]; slot 10 zero-fills pad rows ---
    TP tp;
    int tblk = 0;
    auto addT = [&](int i, const float* s, unsigned short* dst, int K, int N) {
        int nb = (K * N + 255) / 256;
        tp.t[i] = TD{s, dst, K, N, nb};
        tblk += nb;
    };
    addT(0, conv_in_w, WCAT, DM, DM);
    addT(1, x_proj_w, WCAT + 512 * DM, DM, DMAMBA);
    addT(2, dt_w, WCAT + 768 * DM, DM, DMAMBA);
    addT(3, B_w, WCAT + 1024 * DM, DM, DST);
    addT(4, C_w, WCAT + 1088 * DM, DM, DST);
    addT(5, ssm_out_w, SSMT, DMAMBA, DMAMBA);
    addT(6, out_proj_w, OUTPT, DM, DM);
    addT(7, w1, W1T, DM, FFN_D);
    addT(8, w3, W3T, DM, FFN_D);
    addT(9, w2, W2T, FFN_D, DM);
    addT(10, nullptr, WCAT + 1152 * DM, 128, DM);   // zero rows 1152..1279
    transpose_all_k<<<tblk, 256, 0, stream>>>(tp);

    // --- pipeline ---
    rmsnorm1_k<<<MTOK / 4, 256, 0, stream>>>(x, pre_norm_w, XN);

    gemm256<0><<<dim3(NPROJP / 256, MTOK / 256), 512, 0, stream>>>(
        XN, WCAT, nullptr, PROJ, nullptr, DM, NPROJP);

    mamba_prep_k<<<MTOK / 4, 256, 0, stream>>>(PROJ, dt_b, A_log, conv_dw_w, conv_dw_b,
                                               DECAY, INP, CMN, MIXIN);

    scan_chunk_k<<<BSZ * NCH, 256, 0, stream>>>(DECAY, INP, PP, SS);
    scan_prefix_k<<<BSZ, 256, 0, stream>>>(PP, SS, CARRY);
    scan_finish_k<<<BSZ * NCH, 256, 0, stream>>>(DECAY, INP, CARRY, CMN, Dw, PROJ, Y);

    gemm_nt<1><<<dim3(DMAMBA / 128, MTOK / 128), 256, 0, stream>>>(
        Y, SSMT, (void*)(MIXIN + 256), DMAMBA, DM);

    gemm256<0><<<dim3(DM / 256, MTOK / 256), 512, 0, stream>>>(
        MIXIN, OUTPT, nullptr, MIXER, nullptr, DM, DM);

    update_norm_k<<<MTOK / 4, 256, 0, stream>>>(x, velocity, MIXER, log_beta, ffn_norm_w,
                                                outX, outV, NORMED);

    // FFN: H1 = normed@w1 (bf16); ACT = silu(H1) * (normed@w3); x += ACT@w2
    gemm256<1><<<dim3(FFN_D / 256, MTOK / 256), 512, 0, stream>>>(
        NORMED, W1T, nullptr, H1, nullptr, DM, FFN_D);

    gemm256<2><<<dim3(FFN_D / 256, MTOK / 256), 512, 0, stream>>>(
        NORMED, W3T, H1, ACT, nullptr, DM, FFN_D);

    gemm256<3><<<dim3(DM / 256, MTOK / 256), 512, 0, stream>>>(
        ACT, W2T, nullptr, (void*)outX, (const float*)outX, FFN_D, DM);
}